// Round 2
// baseline (730.057 us; speedup 1.0000x reference)
//
#include <hip/hip_runtime.h>

#define NNODE 1000
#define D 64
#define K_TOP 20
#define NROWS 32000   // B*N = 32*1000

// ---------------- inverse norms (f64) ----------------
__global__ void norms_kernel(const float* __restrict__ e0, const float* __restrict__ e1,
                             const float* __restrict__ e2, double* __restrict__ inv_nrm) {
    int g = blockIdx.y;
    const float* e = (g == 0) ? e0 : ((g == 1) ? e1 : e2);
    int j = blockIdx.x * 256 + threadIdx.x;
    if (j < NNODE) {
        double s = 0.0;
        #pragma unroll
        for (int k = 0; k < D; ++k) { double v = (double)e[j * D + k]; s += v * v; }
        inv_nrm[g * NNODE + j] = 1.0 / sqrt(s);
    }
}

// ---------------- top-20 cosine, one wave per row, registers only ----------------
// lane holds 16 candidates j = t*64 + lane (compile-time register indexing).
// f64 dots for exact ranking vs numpy; tie -> smaller index (jax top_k rule).
__global__ void topk_all_kernel(const float* __restrict__ e0, const float* __restrict__ e1,
                                const float* __restrict__ e2, const double* __restrict__ inv_nrm,
                                int* __restrict__ idxM, int* __restrict__ idxP,
                                int* __restrict__ idxN, float* __restrict__ idxf_out) {
    int g = blockIdx.y;
    const float* emb = (g == 0) ? e0 : ((g == 1) ? e1 : e2);
    int* idx_out = (g == 0) ? idxM : ((g == 1) ? idxP : idxN);
    const double* inv = inv_nrm + g * NNODE;

    __shared__ float srow[4][D];
    int tid = threadIdx.x;
    int w = tid >> 6, l = tid & 63;
    int i = blockIdx.x * 4 + w;          // row 0..999 (grid.x = 250)
    srow[w][l] = emb[i * D + l];
    __syncthreads();

    double inv_i = inv[i];

    // cache own row in registers (16 x float4)
    float4 r[16];
    const float4* sr4 = (const float4*)srow[w];
    #pragma unroll
    for (int q = 0; q < 16; ++q) r[q] = sr4[q];

    // 16 cosines per lane
    double val[16];
    #pragma unroll
    for (int t = 0; t < 16; ++t) {
        int j = t * 64 + l;
        int jc = (j < NNODE) ? j : 0;
        const float4* ej = (const float4*)(emb + (size_t)jc * D);
        double acc = 0.0;
        #pragma unroll
        for (int q = 0; q < 16; ++q) {
            float4 v = ej[q];
            acc = fma((double)v.x, (double)r[q].x, acc);
            acc = fma((double)v.y, (double)r[q].y, acc);
            acc = fma((double)v.z, (double)r[q].z, acc);
            acc = fma((double)v.w, (double)r[q].w, acc);
        }
        val[t] = (j < NNODE) ? acc * inv_i * inv[jc] : -1.0e301;
    }

    // local max (strict > : ascending t => smaller j wins ties within lane)
    double lmax = -1.0e302; int lidx = 0x7fffffff;
    #pragma unroll
    for (int t = 0; t < 16; ++t)
        if (val[t] > lmax) { lmax = val[t]; lidx = t * 64 + l; }

    for (int rr = 0; rr < K_TOP; ++rr) {
        // wave-wide arg-max with tie -> smaller index
        double bv = lmax; int bi = lidx;
        #pragma unroll
        for (int s = 1; s < 64; s <<= 1) {
            double ov = __shfl_xor(bv, s, 64);
            int    oi = __shfl_xor(bi, s, 64);
            if (ov > bv || (ov == bv && oi < bi)) { bv = ov; bi = oi; }
        }
        if (l == 0) {
            idx_out[i * K_TOP + rr] = bi;
            if (g == 0) idxf_out[i * K_TOP + rr] = (float)bi;
        }
        if (bi == lidx) {  // exactly the winning lane
            #pragma unroll
            for (int t = 0; t < 16; ++t)
                if (t * 64 + l == bi) val[t] = -1.0e301;
            lmax = -1.0e302; lidx = 0x7fffffff;
            #pragma unroll
            for (int t = 0; t < 16; ++t)
                if (val[t] > lmax) { lmax = val[t]; lidx = t * 64 + l; }
        }
    }
}

// ---------------- row GEMM: out[row][c] = bias[c] + sum_k X[row][xoff+k]*W[k][c] ----------------
template <int K>
__global__ void rowgemm_kernel(const float* __restrict__ X, int ldx, int xoff,
                               const float* __restrict__ W, const float* __restrict__ bias,
                               float* __restrict__ out) {
    __shared__ float Ws[K * D];
    __shared__ float xs[4][K];
    int tid = threadIdx.x;
    for (int e = tid; e < K * D; e += 256) Ws[e] = W[e];
    int base_row = blockIdx.x * 4;
    for (int e = tid; e < 4 * K; e += 256) {
        int r = e / K, k = e % K;
        xs[r][k] = X[(size_t)(base_row + r) * ldx + xoff + k];
    }
    __syncthreads();
    int lr = tid >> 6, c = tid & 63;
    float acc = bias[c];
    #pragma unroll
    for (int k = 0; k < K; ++k) acc = fmaf(xs[lr][k], Ws[k * D + c], acc);
    out[(size_t)(base_row + lr) * D + c] = acc;
}

// ---------------- GCN gather-mean-relu (+optional x output), t = y*emb ----------------
__global__ void gcn_kernel(const float* __restrict__ h, const int* __restrict__ idx,
                           const float* __restrict__ emb, float* __restrict__ t_out,
                           float* __restrict__ x_out) {
    __shared__ int nbrs[4][K_TOP];
    int tid = threadIdx.x;
    int lr = tid >> 6, c = tid & 63;
    int row = blockIdx.x * 4 + lr;
    int b = row / NNODE, i = row % NNODE;
    if (c < K_TOP) nbrs[lr][c] = idx[i * K_TOP + c];
    __syncthreads();
    const float* hb = h + (size_t)b * NNODE * D;
    float s = 0.f;
    #pragma unroll
    for (int t = 0; t < K_TOP; ++t) s += hb[(size_t)nbrs[lr][t] * D + c];
    float y = fmaxf(s * (1.0f / 20.0f), 0.f);
    if (x_out) x_out[(size_t)row * D + c] = y;
    t_out[(size_t)row * D + c] = y * emb[i * D + c];
}

// ---------------- BN stats: per-block partial sums (f64, deterministic) ----------------
__global__ void bn_partial_kernel(const float* __restrict__ t, double* __restrict__ psum,
                                  double* __restrict__ psq) {
    __shared__ double sh[256], sh2[256];
    int tid = threadIdx.x;
    const float* base = t + (size_t)blockIdx.x * 125 * D;
    double s = 0.0, ss = 0.0;
    for (int e = tid; e < 125 * D; e += 256) {
        double v = (double)base[e];
        s += v; ss += v * v;
    }
    sh[tid] = s; sh2[tid] = ss;
    __syncthreads();
    if (tid < 128) { sh[tid] += sh[tid + 128]; sh2[tid] += sh2[tid + 128]; }
    __syncthreads();
    if (tid < 64) {
        psum[(size_t)blockIdx.x * D + tid] = sh[tid] + sh[tid + 64];
        psq[(size_t)blockIdx.x * D + tid] = sh2[tid] + sh2[tid + 64];
    }
}

__global__ void bn_final_kernel(const double* __restrict__ psum, const double* __restrict__ psq,
                                const float* __restrict__ g, const float* __restrict__ beta,
                                float* __restrict__ ss_out) {
    int c = threadIdx.x;
    if (c < D) {
        double s = 0.0, sq = 0.0;
        for (int b2 = 0; b2 < 256; ++b2) { s += psum[b2 * D + c]; sq += psq[b2 * D + c]; }
        const double n = (double)NROWS;
        double mu = s / n;
        double var = sq / n - mu * mu;
        double inv = 1.0 / sqrt(var + 1e-5);
        double sc = (double)g[c] * inv;
        ss_out[c] = (float)sc;
        ss_out[D + c] = (float)((double)beta[c] - mu * sc);
    }
}

// ---------------- BN-apply + 64x64 GEMM ----------------
__global__ void bn_gemm64_kernel(const float* __restrict__ t, const float* __restrict__ ss,
                                 const float* __restrict__ W, const float* __restrict__ bias,
                                 float* __restrict__ out) {
    __shared__ float Ws[D * D];
    __shared__ float v[4][D];
    int tid = threadIdx.x;
    for (int e = tid; e < D * D; e += 256) Ws[e] = W[e];
    int lr = tid >> 6, c = tid & 63;
    int row = blockIdx.x * 4 + lr;
    float x = t[(size_t)row * D + c];
    v[lr][c] = fmaxf(fmaf(x, ss[c], ss[D + c]), 0.f);
    __syncthreads();
    float acc = bias[c];
    #pragma unroll
    for (int k = 0; k < D; ++k) acc = fmaf(v[lr][k], Ws[k * D + c], acc);
    out[(size_t)row * D + c] = acc;
}

// ---------------- BN-apply + 64->1 projection ----------------
__global__ void phy_out_kernel(const float* __restrict__ t, const float* __restrict__ ss,
                               const float* __restrict__ Wp, const float* __restrict__ bp,
                               float* __restrict__ out) {
    int tid = threadIdx.x;
    int lr = tid >> 6, c = tid & 63;
    int row = blockIdx.x * 4 + lr;
    float x = t[(size_t)row * D + c];
    float bnv = fmaxf(fmaf(x, ss[c], ss[D + c]), 0.f);
    float p = bnv * Wp[c];
    #pragma unroll
    for (int s = 32; s > 0; s >>= 1) p += __shfl_down(p, s, 64);
    if (c == 0) out[row] = p + bp[0];
}

// ---------------- BN-apply + 64->3 projection ----------------
__global__ void net_out_kernel(const float* __restrict__ t, const float* __restrict__ ss,
                               const float* __restrict__ Wn, const float* __restrict__ bn_,
                               float* __restrict__ out) {
    int tid = threadIdx.x;
    int lr = tid >> 6, c = tid & 63;
    int row = blockIdx.x * 4 + lr;
    float x = t[(size_t)row * D + c];
    float bnv = fmaxf(fmaf(x, ss[c], ss[D + c]), 0.f);
    float p0 = bnv * Wn[c * 3 + 0];
    float p1 = bnv * Wn[c * 3 + 1];
    float p2 = bnv * Wn[c * 3 + 2];
    #pragma unroll
    for (int s = 32; s > 0; s >>= 1) {
        p0 += __shfl_down(p0, s, 64);
        p1 += __shfl_down(p1, s, 64);
        p2 += __shfl_down(p2, s, 64);
    }
    if (c == 0) {
        out[(size_t)row * 3 + 0] = p0 + bn_[0];
        out[(size_t)row * 3 + 1] = p1 + bn_[1];
        out[(size_t)row * 3 + 2] = p2 + bn_[2];
    }
}

extern "C" void kernel_launch(void* const* d_in, const int* in_sizes, int n_in,
                              void* d_out, int out_size, void* d_ws, size_t ws_size,
                              hipStream_t stream) {
    const float* data    = (const float*)d_in[0];
    // d_in[1..3] = edge_index arrays: unused by the reference
    const float* mul_emb = (const float*)d_in[4];
    const float* phy_emb = (const float*)d_in[5];
    const float* net_emb = (const float*)d_in[6];
    const float* W_share = (const float*)d_in[7];
    const float* b_share = (const float*)d_in[8];
    const float* W_phy   = (const float*)d_in[9];
    const float* b_phy   = (const float*)d_in[10];
    const float* W_net   = (const float*)d_in[11];
    const float* b_net   = (const float*)d_in[12];
    const float* g_mul   = (const float*)d_in[13];
    const float* be_mul  = (const float*)d_in[14];
    const float* g_phy   = (const float*)d_in[15];
    const float* be_phy  = (const float*)d_in[16];
    const float* g_net   = (const float*)d_in[17];
    const float* be_net  = (const float*)d_in[18];
    const float* W_out   = (const float*)d_in[19];
    const float* b_out   = (const float*)d_in[20];
    const float* W_pout  = (const float*)d_in[21];
    const float* b_pout  = (const float*)d_in[22];
    const float* W_nout  = (const float*)d_in[23];
    const float* b_nout  = (const float*)d_in[24];

    float* outf = (float*)d_out;
    float* out_phy  = outf;            // 32000
    float* out_net  = outf + 32000;    // 96000
    float* out_idx  = outf + 128000;   // 20000 (idx_mul as floats)
    float* out_xnet = outf + 148000;   // 2048000
    float* out_xphy = outf + 2196000;  // 2048000

    char* ws = (char*)d_ws;
    size_t off = 0;
    auto alloc = [&](size_t bytes) -> void* {
        void* p = (void*)(ws + off);
        off += bytes;
        off = (off + 255) & ~(size_t)255;
        return p;
    };
    int* idxM = (int*)alloc(20000 * 4);
    int* idxP = (int*)alloc(20000 * 4);
    int* idxN = (int*)alloc(20000 * 4);
    double* inv_nrm = (double*)alloc(3000 * 8);
    double* psum = (double*)alloc(256 * 64 * 8);
    double* psq  = (double*)alloc(256 * 64 * 8);
    float* ssM = (float*)alloc(128 * 4);
    float* ssP = (float*)alloc(128 * 4);
    float* ssN = (float*)alloc(128 * 4);
    float* A  = (float*)alloc((size_t)NROWS * D * 4);  // h_share -> h_phy
    float* Bb = (float*)alloc((size_t)NROWS * D * 4);  // t_mul   -> h_net
    float* C  = (float*)alloc((size_t)NROWS * D * 4);  // out_mid -> t_phy
    float* Dd = (float*)alloc((size_t)NROWS * D * 4);  // t_net

    // 1. graphs (f64 cosine, exact ranking), all three in one dispatch
    norms_kernel<<<dim3(4, 3), 256, 0, stream>>>(mul_emb, phy_emb, net_emb, inv_nrm);
    topk_all_kernel<<<dim3(250, 3), 256, 0, stream>>>(mul_emb, phy_emb, net_emb, inv_nrm,
                                                      idxM, idxP, idxN, out_idx);

    // 2. mul path
    rowgemm_kernel<60><<<8000, 256, 0, stream>>>(data, 60, 0, W_share, b_share, A);
    gcn_kernel<<<8000, 256, 0, stream>>>(A, idxM, mul_emb, Bb, (float*)nullptr);
    bn_partial_kernel<<<256, 256, 0, stream>>>(Bb, psum, psq);
    bn_final_kernel<<<1, 64, 0, stream>>>(psum, psq, g_mul, be_mul, ssM);
    bn_gemm64_kernel<<<8000, 256, 0, stream>>>(Bb, ssM, W_out, b_out, C);

    // 3. phy / net heads
    rowgemm_kernel<16><<<8000, 256, 0, stream>>>(C, 64, 0, W_phy, b_phy, A);
    rowgemm_kernel<48><<<8000, 256, 0, stream>>>(C, 64, 16, W_net, b_net, Bb);
    gcn_kernel<<<8000, 256, 0, stream>>>(A, idxP, phy_emb, C, out_xphy);
    gcn_kernel<<<8000, 256, 0, stream>>>(Bb, idxN, net_emb, Dd, out_xnet);

    bn_partial_kernel<<<256, 256, 0, stream>>>(C, psum, psq);
    bn_final_kernel<<<1, 64, 0, stream>>>(psum, psq, g_phy, be_phy, ssP);
    phy_out_kernel<<<8000, 256, 0, stream>>>(C, ssP, W_pout, b_pout, out_phy);

    bn_partial_kernel<<<256, 256, 0, stream>>>(Dd, psum, psq);
    bn_final_kernel<<<1, 64, 0, stream>>>(psum, psq, g_net, be_net, ssN);
    net_out_kernel<<<8000, 256, 0, stream>>>(Dd, ssN, W_nout, b_nout, out_net);
}

// Round 3
// 726.333 us; speedup vs baseline: 1.0051x; 1.0051x over previous
//
#include <hip/hip_runtime.h>

#define NNODE 1000
#define D 64
#define K_TOP 20
#define NROWS 32000   // B*N = 32*1000

// ---------------- inverse norms (f64) ----------------
__global__ void norms_kernel(const float* __restrict__ e0, const float* __restrict__ e1,
                             const float* __restrict__ e2, double* __restrict__ inv_nrm) {
    int g = blockIdx.y;
    const float* e = (g == 0) ? e0 : ((g == 1) ? e1 : e2);
    int j = blockIdx.x * 256 + threadIdx.x;
    if (j < NNODE) {
        double s = 0.0;
        #pragma unroll
        for (int k = 0; k < D; ++k) { double v = (double)e[j * D + k]; s += v * v; }
        inv_nrm[g * NNODE + j] = 1.0 / sqrt(s);
    }
}

// ---------------- top-20 cosine, one wave per row ----------------
// lane holds 16 candidates j = t*64 + lane; val[16] statically indexed -> registers.
// Own row stays in LDS (broadcast reads). f64 for exact ranking vs numpy;
// tie -> smaller index (jax top_k rule). launch_bounds caps pressure w/o spill.
__global__ void __launch_bounds__(256, 4)
topk_all_kernel(const float* __restrict__ e0, const float* __restrict__ e1,
                const float* __restrict__ e2, const double* __restrict__ inv_nrm,
                int* __restrict__ idxM, int* __restrict__ idxP,
                int* __restrict__ idxN, float* __restrict__ idxf_out) {
    int g = blockIdx.y;
    const float* emb = (g == 0) ? e0 : ((g == 1) ? e1 : e2);
    int* idx_out = (g == 0) ? idxM : ((g == 1) ? idxP : idxN);
    const double* inv = inv_nrm + g * NNODE;

    __shared__ float srow[4][D];
    int tid = threadIdx.x;
    int w = tid >> 6, l = tid & 63;
    int i = blockIdx.x * 4 + w;          // row 0..999 (grid.x = 250)
    srow[w][l] = emb[i * D + l];
    __syncthreads();

    double inv_i = inv[i];
    const float4* sr4 = (const float4*)srow[w];

    // 16 cosines per lane; own-row factors come from LDS (broadcast, no reg cache)
    double val[16];
    #pragma unroll
    for (int t = 0; t < 16; ++t) {
        int j = t * 64 + l;
        int jc = (j < NNODE) ? j : 0;
        const float4* ej = (const float4*)(emb + (size_t)jc * D);
        double acc = 0.0;
        #pragma unroll
        for (int q = 0; q < 16; ++q) {
            float4 v = ej[q];
            float4 r = sr4[q];            // LDS broadcast read
            acc = fma((double)v.x, (double)r.x, acc);
            acc = fma((double)v.y, (double)r.y, acc);
            acc = fma((double)v.z, (double)r.z, acc);
            acc = fma((double)v.w, (double)r.w, acc);
        }
        val[t] = (j < NNODE) ? acc * inv_i * inv[jc] : -1.0e301;
    }

    // local max (strict > : ascending t => smaller j wins ties within lane)
    double lmax = -1.0e302; int lidx = 0x7fffffff;
    #pragma unroll
    for (int t = 0; t < 16; ++t)
        if (val[t] > lmax) { lmax = val[t]; lidx = t * 64 + l; }

    for (int rr = 0; rr < K_TOP; ++rr) {
        // wave-wide arg-max with tie -> smaller index
        double bv = lmax; int bi = lidx;
        #pragma unroll
        for (int s = 1; s < 64; s <<= 1) {
            double ov = __shfl_xor(bv, s, 64);
            int    oi = __shfl_xor(bi, s, 64);
            if (ov > bv || (ov == bv && oi < bi)) { bv = ov; bi = oi; }
        }
        if (l == 0) {
            idx_out[i * K_TOP + rr] = bi;
            if (g == 0) idxf_out[i * K_TOP + rr] = (float)bi;
        }
        if (bi == lidx) {  // exactly the winning lane
            #pragma unroll
            for (int t = 0; t < 16; ++t)
                if (t * 64 + l == bi) val[t] = -1.0e301;
            lmax = -1.0e302; lidx = 0x7fffffff;
            #pragma unroll
            for (int t = 0; t < 16; ++t)
                if (val[t] > lmax) { lmax = val[t]; lidx = t * 64 + l; }
        }
    }
}

// ---------------- row GEMM: out[row][c] = bias[c] + sum_k X[row][xoff+k]*W[k][c] ----------------
template <int K>
__global__ void rowgemm_kernel(const float* __restrict__ X, int ldx, int xoff,
                               const float* __restrict__ W, const float* __restrict__ bias,
                               float* __restrict__ out) {
    __shared__ float Ws[K * D];
    __shared__ float xs[4][K];
    int tid = threadIdx.x;
    for (int e = tid; e < K * D; e += 256) Ws[e] = W[e];
    int base_row = blockIdx.x * 4;
    for (int e = tid; e < 4 * K; e += 256) {
        int r = e / K, k = e % K;
        xs[r][k] = X[(size_t)(base_row + r) * ldx + xoff + k];
    }
    __syncthreads();
    int lr = tid >> 6, c = tid & 63;
    float acc = bias[c];
    #pragma unroll
    for (int k = 0; k < K; ++k) acc = fmaf(xs[lr][k], Ws[k * D + c], acc);
    out[(size_t)(base_row + lr) * D + c] = acc;
}

// ---------------- GCN gather-mean-relu (+optional x output), t = y*emb ----------------
__global__ void gcn_kernel(const float* __restrict__ h, const int* __restrict__ idx,
                           const float* __restrict__ emb, float* __restrict__ t_out,
                           float* __restrict__ x_out) {
    __shared__ int nbrs[4][K_TOP];
    int tid = threadIdx.x;
    int lr = tid >> 6, c = tid & 63;
    int row = blockIdx.x * 4 + lr;
    int b = row / NNODE, i = row % NNODE;
    if (c < K_TOP) nbrs[lr][c] = idx[i * K_TOP + c];
    __syncthreads();
    const float* hb = h + (size_t)b * NNODE * D;
    float s = 0.f;
    #pragma unroll
    for (int t = 0; t < K_TOP; ++t) s += hb[(size_t)nbrs[lr][t] * D + c];
    float y = fmaxf(s * (1.0f / 20.0f), 0.f);
    if (x_out) x_out[(size_t)row * D + c] = y;
    t_out[(size_t)row * D + c] = y * emb[i * D + c];
}

// ---------------- BN stats: per-block partial sums (f64, deterministic) ----------------
__global__ void bn_partial_kernel(const float* __restrict__ t, double* __restrict__ psum,
                                  double* __restrict__ psq) {
    __shared__ double sh[256], sh2[256];
    int tid = threadIdx.x;
    const float* base = t + (size_t)blockIdx.x * 125 * D;
    double s = 0.0, ss = 0.0;
    for (int e = tid; e < 125 * D; e += 256) {
        double v = (double)base[e];
        s += v; ss += v * v;
    }
    sh[tid] = s; sh2[tid] = ss;
    __syncthreads();
    if (tid < 128) { sh[tid] += sh[tid + 128]; sh2[tid] += sh2[tid + 128]; }
    __syncthreads();
    if (tid < 64) {
        psum[(size_t)blockIdx.x * D + tid] = sh[tid] + sh[tid + 64];
        psq[(size_t)blockIdx.x * D + tid] = sh2[tid] + sh2[tid + 64];
    }
}

__global__ void bn_final_kernel(const double* __restrict__ psum, const double* __restrict__ psq,
                                const float* __restrict__ g, const float* __restrict__ beta,
                                float* __restrict__ ss_out) {
    int c = threadIdx.x;
    if (c < D) {
        double s = 0.0, sq = 0.0;
        for (int b2 = 0; b2 < 256; ++b2) { s += psum[b2 * D + c]; sq += psq[b2 * D + c]; }
        const double n = (double)NROWS;
        double mu = s / n;
        double var = sq / n - mu * mu;
        double inv = 1.0 / sqrt(var + 1e-5);
        double sc = (double)g[c] * inv;
        ss_out[c] = (float)sc;
        ss_out[D + c] = (float)((double)beta[c] - mu * sc);
    }
}

// ---------------- BN-apply + 64x64 GEMM ----------------
__global__ void bn_gemm64_kernel(const float* __restrict__ t, const float* __restrict__ ss,
                                 const float* __restrict__ W, const float* __restrict__ bias,
                                 float* __restrict__ out) {
    __shared__ float Ws[D * D];
    __shared__ float v[4][D];
    int tid = threadIdx.x;
    for (int e = tid; e < D * D; e += 256) Ws[e] = W[e];
    int lr = tid >> 6, c = tid & 63;
    int row = blockIdx.x * 4 + lr;
    float x = t[(size_t)row * D + c];
    v[lr][c] = fmaxf(fmaf(x, ss[c], ss[D + c]), 0.f);
    __syncthreads();
    float acc = bias[c];
    #pragma unroll
    for (int k = 0; k < D; ++k) acc = fmaf(v[lr][k], Ws[k * D + c], acc);
    out[(size_t)row * D + c] = acc;
}

// ---------------- BN-apply + 64->1 projection ----------------
__global__ void phy_out_kernel(const float* __restrict__ t, const float* __restrict__ ss,
                               const float* __restrict__ Wp, const float* __restrict__ bp,
                               float* __restrict__ out) {
    int tid = threadIdx.x;
    int lr = tid >> 6, c = tid & 63;
    int row = blockIdx.x * 4 + lr;
    float x = t[(size_t)row * D + c];
    float bnv = fmaxf(fmaf(x, ss[c], ss[D + c]), 0.f);
    float p = bnv * Wp[c];
    #pragma unroll
    for (int s = 32; s > 0; s >>= 1) p += __shfl_down(p, s, 64);
    if (c == 0) out[row] = p + bp[0];
}

// ---------------- BN-apply + 64->3 projection ----------------
__global__ void net_out_kernel(const float* __restrict__ t, const float* __restrict__ ss,
                               const float* __restrict__ Wn, const float* __restrict__ bn_,
                               float* __restrict__ out) {
    int tid = threadIdx.x;
    int lr = tid >> 6, c = tid & 63;
    int row = blockIdx.x * 4 + lr;
    float x = t[(size_t)row * D + c];
    float bnv = fmaxf(fmaf(x, ss[c], ss[D + c]), 0.f);
    float p0 = bnv * Wn[c * 3 + 0];
    float p1 = bnv * Wn[c * 3 + 1];
    float p2 = bnv * Wn[c * 3 + 2];
    #pragma unroll
    for (int s = 32; s > 0; s >>= 1) {
        p0 += __shfl_down(p0, s, 64);
        p1 += __shfl_down(p1, s, 64);
        p2 += __shfl_down(p2, s, 64);
    }
    if (c == 0) {
        out[(size_t)row * 3 + 0] = p0 + bn_[0];
        out[(size_t)row * 3 + 1] = p1 + bn_[1];
        out[(size_t)row * 3 + 2] = p2 + bn_[2];
    }
}

extern "C" void kernel_launch(void* const* d_in, const int* in_sizes, int n_in,
                              void* d_out, int out_size, void* d_ws, size_t ws_size,
                              hipStream_t stream) {
    const float* data    = (const float*)d_in[0];
    // d_in[1..3] = edge_index arrays: unused by the reference
    const float* mul_emb = (const float*)d_in[4];
    const float* phy_emb = (const float*)d_in[5];
    const float* net_emb = (const float*)d_in[6];
    const float* W_share = (const float*)d_in[7];
    const float* b_share = (const float*)d_in[8];
    const float* W_phy   = (const float*)d_in[9];
    const float* b_phy   = (const float*)d_in[10];
    const float* W_net   = (const float*)d_in[11];
    const float* b_net   = (const float*)d_in[12];
    const float* g_mul   = (const float*)d_in[13];
    const float* be_mul  = (const float*)d_in[14];
    const float* g_phy   = (const float*)d_in[15];
    const float* be_phy  = (const float*)d_in[16];
    const float* g_net   = (const float*)d_in[17];
    const float* be_net  = (const float*)d_in[18];
    const float* W_out   = (const float*)d_in[19];
    const float* b_out   = (const float*)d_in[20];
    const float* W_pout  = (const float*)d_in[21];
    const float* b_pout  = (const float*)d_in[22];
    const float* W_nout  = (const float*)d_in[23];
    const float* b_nout  = (const float*)d_in[24];

    float* outf = (float*)d_out;
    float* out_phy  = outf;            // 32000
    float* out_net  = outf + 32000;    // 96000
    float* out_idx  = outf + 128000;   // 20000 (idx_mul as floats)
    float* out_xnet = outf + 148000;   // 2048000
    float* out_xphy = outf + 2196000;  // 2048000

    char* ws = (char*)d_ws;
    size_t off = 0;
    auto alloc = [&](size_t bytes) -> void* {
        void* p = (void*)(ws + off);
        off += bytes;
        off = (off + 255) & ~(size_t)255;
        return p;
    };
    int* idxM = (int*)alloc(20000 * 4);
    int* idxP = (int*)alloc(20000 * 4);
    int* idxN = (int*)alloc(20000 * 4);
    double* inv_nrm = (double*)alloc(3000 * 8);
    double* psum = (double*)alloc(256 * 64 * 8);
    double* psq  = (double*)alloc(256 * 64 * 8);
    float* ssM = (float*)alloc(128 * 4);
    float* ssP = (float*)alloc(128 * 4);
    float* ssN = (float*)alloc(128 * 4);
    float* A  = (float*)alloc((size_t)NROWS * D * 4);  // h_share -> h_phy
    float* Bb = (float*)alloc((size_t)NROWS * D * 4);  // t_mul   -> h_net
    float* C  = (float*)alloc((size_t)NROWS * D * 4);  // out_mid -> t_phy
    float* Dd = (float*)alloc((size_t)NROWS * D * 4);  // t_net

    // 1. graphs (f64 cosine, exact ranking), all three in one dispatch
    norms_kernel<<<dim3(4, 3), 256, 0, stream>>>(mul_emb, phy_emb, net_emb, inv_nrm);
    topk_all_kernel<<<dim3(250, 3), 256, 0, stream>>>(mul_emb, phy_emb, net_emb, inv_nrm,
                                                      idxM, idxP, idxN, out_idx);

    // 2. mul path
    rowgemm_kernel<60><<<8000, 256, 0, stream>>>(data, 60, 0, W_share, b_share, A);
    gcn_kernel<<<8000, 256, 0, stream>>>(A, idxM, mul_emb, Bb, (float*)nullptr);
    bn_partial_kernel<<<256, 256, 0, stream>>>(Bb, psum, psq);
    bn_final_kernel<<<1, 64, 0, stream>>>(psum, psq, g_mul, be_mul, ssM);
    bn_gemm64_kernel<<<8000, 256, 0, stream>>>(Bb, ssM, W_out, b_out, C);

    // 3. phy / net heads
    rowgemm_kernel<16><<<8000, 256, 0, stream>>>(C, 64, 0, W_phy, b_phy, A);
    rowgemm_kernel<48><<<8000, 256, 0, stream>>>(C, 64, 16, W_net, b_net, Bb);
    gcn_kernel<<<8000, 256, 0, stream>>>(A, idxP, phy_emb, C, out_xphy);
    gcn_kernel<<<8000, 256, 0, stream>>>(Bb, idxN, net_emb, Dd, out_xnet);

    bn_partial_kernel<<<256, 256, 0, stream>>>(C, psum, psq);
    bn_final_kernel<<<1, 64, 0, stream>>>(psum, psq, g_phy, be_phy, ssP);
    phy_out_kernel<<<8000, 256, 0, stream>>>(C, ssP, W_pout, b_pout, out_phy);

    bn_partial_kernel<<<256, 256, 0, stream>>>(Dd, psum, psq);
    bn_final_kernel<<<1, 64, 0, stream>>>(psum, psq, g_net, be_net, ssN);
    net_out_kernel<<<8000, 256, 0, stream>>>(Dd, ssN, W_nout, b_nout, out_net);
}

// Round 4
// 318.385 us; speedup vs baseline: 2.2930x; 2.2813x over previous
//
#include <hip/hip_runtime.h>

#define NNODE 1000
#define D 64
#define K_TOP 20
#define NROWS 32000   // B*N = 32*1000

// ---------------- inverse norms (f64) ----------------
__global__ void norms_kernel(const float* __restrict__ e0, const float* __restrict__ e1,
                             const float* __restrict__ e2, double* __restrict__ inv_nrm) {
    int g = blockIdx.y;
    const float* e = (g == 0) ? e0 : ((g == 1) ? e1 : e2);
    int j = blockIdx.x * 256 + threadIdx.x;
    if (j < NNODE) {
        double s = 0.0;
        #pragma unroll
        for (int k = 0; k < D; ++k) { double v = (double)e[j * D + k]; s += v * v; }
        inv_nrm[g * NNODE + j] = 1.0 / sqrt(s);
    }
}

// ---------------- top-20 cosine: one block per query row ----------------
// Each thread owns 4 candidates (val[4] = 8 VGPRs -> no scratch). f64 dots,
// identical FMA order to prior passing rounds -> bit-identical cosines.
// Selection: wave shfl argmax -> 4-entry LDS -> redundant block reduce.
// Tie rule everywhere: equal value -> smaller index (jax top_k).
__global__ void topk_all_kernel(const float* __restrict__ e0, const float* __restrict__ e1,
                                const float* __restrict__ e2, const double* __restrict__ inv_nrm,
                                int* __restrict__ idxM, int* __restrict__ idxP,
                                int* __restrict__ idxN, float* __restrict__ idxf_out) {
    int g = blockIdx.y;
    const float* emb = (g == 0) ? e0 : ((g == 1) ? e1 : e2);
    int* idx_out = (g == 0) ? idxM : ((g == 1) ? idxP : idxN);
    const double* inv = inv_nrm + g * NNODE;

    int i = blockIdx.x;            // query row, grid.x = 1000
    int tid = threadIdx.x;
    int w = tid >> 6, l = tid & 63;

    __shared__ float srow[D];
    __shared__ double sbv[2][4];
    __shared__ int sbi[2][4];
    if (tid < D) srow[tid] = emb[i * D + tid];
    __syncthreads();

    double inv_i = inv[i];
    const float4* sr4 = (const float4*)srow;

    // 4 cosines per thread; query row broadcast from LDS
    double val[4];
    #pragma unroll
    for (int t = 0; t < 4; ++t) {
        int j = t * 256 + tid;
        int jc = (j < NNODE) ? j : 0;
        const float4* ej = (const float4*)(emb + (size_t)jc * D);
        double acc = 0.0;
        #pragma unroll
        for (int q = 0; q < 16; ++q) {
            float4 v = ej[q];
            float4 r = sr4[q];
            acc = fma((double)v.x, (double)r.x, acc);
            acc = fma((double)v.y, (double)r.y, acc);
            acc = fma((double)v.z, (double)r.z, acc);
            acc = fma((double)v.w, (double)r.w, acc);
        }
        val[t] = (j < NNODE) ? acc * inv_i * inv[jc] : -1.0e301;
    }

    // running local max (ascending t, strict > : smaller j wins ties in-thread)
    double lmax = -1.0e302; int lidx = 0x7fffffff;
    #pragma unroll
    for (int t = 0; t < 4; ++t)
        if (val[t] > lmax) { lmax = val[t]; lidx = t * 256 + tid; }

    for (int rr = 0; rr < K_TOP; ++rr) {
        // wave argmax
        double bv = lmax; int bi = lidx;
        #pragma unroll
        for (int s = 1; s < 64; s <<= 1) {
            double ov = __shfl_xor(bv, s, 64);
            int    oi = __shfl_xor(bi, s, 64);
            if (ov > bv || (ov == bv && oi < bi)) { bv = ov; bi = oi; }
        }
        int par = rr & 1;
        if (l == 0) { sbv[par][w] = bv; sbi[par][w] = bi; }
        __syncthreads();
        // block winner, computed redundantly (deterministic) by every thread
        double wv = sbv[par][0]; int wi = sbi[par][0];
        #pragma unroll
        for (int u = 1; u < 4; ++u) {
            double uv = sbv[par][u]; int ui = sbi[par][u];
            if (uv > wv || (uv == wv && ui < wi)) { wv = uv; wi = ui; }
        }
        if (tid == 0) {
            idx_out[i * K_TOP + rr] = wi;
            if (g == 0) idxf_out[i * K_TOP + rr] = (float)wi;
        }
        if (wi == lidx) {   // owning thread invalidates + rescans its 4 regs
            #pragma unroll
            for (int t = 0; t < 4; ++t)
                if (t * 256 + tid == wi) val[t] = -1.0e301;
            lmax = -1.0e302; lidx = 0x7fffffff;
            #pragma unroll
            for (int t = 0; t < 4; ++t)
                if (val[t] > lmax) { lmax = val[t]; lidx = t * 256 + tid; }
        }
    }
}

// ---------------- row GEMM: out[row][c] = bias[c] + sum_k X[row][xoff+k]*W[k][c] ----------------
template <int K>
__global__ void rowgemm_kernel(const float* __restrict__ X, int ldx, int xoff,
                               const float* __restrict__ W, const float* __restrict__ bias,
                               float* __restrict__ out) {
    __shared__ float Ws[K * D];
    __shared__ float xs[4][K];
    int tid = threadIdx.x;
    for (int e = tid; e < K * D; e += 256) Ws[e] = W[e];
    int base_row = blockIdx.x * 4;
    for (int e = tid; e < 4 * K; e += 256) {
        int r = e / K, k = e % K;
        xs[r][k] = X[(size_t)(base_row + r) * ldx + xoff + k];
    }
    __syncthreads();
    int lr = tid >> 6, c = tid & 63;
    float acc = bias[c];
    #pragma unroll
    for (int k = 0; k < K; ++k) acc = fmaf(xs[lr][k], Ws[k * D + c], acc);
    out[(size_t)(base_row + lr) * D + c] = acc;
}

// ---------------- GCN gather-mean-relu (+optional x output), t = y*emb ----------------
__global__ void gcn_kernel(const float* __restrict__ h, const int* __restrict__ idx,
                           const float* __restrict__ emb, float* __restrict__ t_out,
                           float* __restrict__ x_out) {
    __shared__ int nbrs[4][K_TOP];
    int tid = threadIdx.x;
    int lr = tid >> 6, c = tid & 63;
    int row = blockIdx.x * 4 + lr;
    int b = row / NNODE, i = row % NNODE;
    if (c < K_TOP) nbrs[lr][c] = idx[i * K_TOP + c];
    __syncthreads();
    const float* hb = h + (size_t)b * NNODE * D;
    float s = 0.f;
    #pragma unroll
    for (int t = 0; t < K_TOP; ++t) s += hb[(size_t)nbrs[lr][t] * D + c];
    float y = fmaxf(s * (1.0f / 20.0f), 0.f);
    if (x_out) x_out[(size_t)row * D + c] = y;
    t_out[(size_t)row * D + c] = y * emb[i * D + c];
}

// ---------------- BN stats: per-block partial sums (f64, deterministic) ----------------
__global__ void bn_partial_kernel(const float* __restrict__ t, double* __restrict__ psum,
                                  double* __restrict__ psq) {
    __shared__ double sh[256], sh2[256];
    int tid = threadIdx.x;
    const float* base = t + (size_t)blockIdx.x * 125 * D;
    double s = 0.0, ss = 0.0;
    for (int e = tid; e < 125 * D; e += 256) {
        double v = (double)base[e];
        s += v; ss += v * v;
    }
    sh[tid] = s; sh2[tid] = ss;
    __syncthreads();
    if (tid < 128) { sh[tid] += sh[tid + 128]; sh2[tid] += sh2[tid + 128]; }
    __syncthreads();
    if (tid < 64) {
        psum[(size_t)blockIdx.x * D + tid] = sh[tid] + sh[tid + 64];
        psq[(size_t)blockIdx.x * D + tid] = sh2[tid] + sh2[tid + 64];
    }
}

__global__ void bn_final_kernel(const double* __restrict__ psum, const double* __restrict__ psq,
                                const float* __restrict__ g, const float* __restrict__ beta,
                                float* __restrict__ ss_out) {
    int c = threadIdx.x;
    if (c < D) {
        double s = 0.0, sq = 0.0;
        for (int b2 = 0; b2 < 256; ++b2) { s += psum[b2 * D + c]; sq += psq[b2 * D + c]; }
        const double n = (double)NROWS;
        double mu = s / n;
        double var = sq / n - mu * mu;
        double inv = 1.0 / sqrt(var + 1e-5);
        double sc = (double)g[c] * inv;
        ss_out[c] = (float)sc;
        ss_out[D + c] = (float)((double)beta[c] - mu * sc);
    }
}

// ---------------- BN-apply + 64x64 GEMM ----------------
__global__ void bn_gemm64_kernel(const float* __restrict__ t, const float* __restrict__ ss,
                                 const float* __restrict__ W, const float* __restrict__ bias,
                                 float* __restrict__ out) {
    __shared__ float Ws[D * D];
    __shared__ float v[4][D];
    int tid = threadIdx.x;
    for (int e = tid; e < D * D; e += 256) Ws[e] = W[e];
    int lr = tid >> 6, c = tid & 63;
    int row = blockIdx.x * 4 + lr;
    float x = t[(size_t)row * D + c];
    v[lr][c] = fmaxf(fmaf(x, ss[c], ss[D + c]), 0.f);
    __syncthreads();
    float acc = bias[c];
    #pragma unroll
    for (int k = 0; k < D; ++k) acc = fmaf(v[lr][k], Ws[k * D + c], acc);
    out[(size_t)row * D + c] = acc;
}

// ---------------- BN-apply + 64->1 projection ----------------
__global__ void phy_out_kernel(const float* __restrict__ t, const float* __restrict__ ss,
                               const float* __restrict__ Wp, const float* __restrict__ bp,
                               float* __restrict__ out) {
    int tid = threadIdx.x;
    int lr = tid >> 6, c = tid & 63;
    int row = blockIdx.x * 4 + lr;
    float x = t[(size_t)row * D + c];
    float bnv = fmaxf(fmaf(x, ss[c], ss[D + c]), 0.f);
    float p = bnv * Wp[c];
    #pragma unroll
    for (int s = 32; s > 0; s >>= 1) p += __shfl_down(p, s, 64);
    if (c == 0) out[row] = p + bp[0];
}

// ---------------- BN-apply + 64->3 projection ----------------
__global__ void net_out_kernel(const float* __restrict__ t, const float* __restrict__ ss,
                               const float* __restrict__ Wn, const float* __restrict__ bn_,
                               float* __restrict__ out) {
    int tid = threadIdx.x;
    int lr = tid >> 6, c = tid & 63;
    int row = blockIdx.x * 4 + lr;
    float x = t[(size_t)row * D + c];
    float bnv = fmaxf(fmaf(x, ss[c], ss[D + c]), 0.f);
    float p0 = bnv * Wn[c * 3 + 0];
    float p1 = bnv * Wn[c * 3 + 1];
    float p2 = bnv * Wn[c * 3 + 2];
    #pragma unroll
    for (int s = 32; s > 0; s >>= 1) {
        p0 += __shfl_down(p0, s, 64);
        p1 += __shfl_down(p1, s, 64);
        p2 += __shfl_down(p2, s, 64);
    }
    if (c == 0) {
        out[(size_t)row * 3 + 0] = p0 + bn_[0];
        out[(size_t)row * 3 + 1] = p1 + bn_[1];
        out[(size_t)row * 3 + 2] = p2 + bn_[2];
    }
}

extern "C" void kernel_launch(void* const* d_in, const int* in_sizes, int n_in,
                              void* d_out, int out_size, void* d_ws, size_t ws_size,
                              hipStream_t stream) {
    const float* data    = (const float*)d_in[0];
    // d_in[1..3] = edge_index arrays: unused by the reference
    const float* mul_emb = (const float*)d_in[4];
    const float* phy_emb = (const float*)d_in[5];
    const float* net_emb = (const float*)d_in[6];
    const float* W_share = (const float*)d_in[7];
    const float* b_share = (const float*)d_in[8];
    const float* W_phy   = (const float*)d_in[9];
    const float* b_phy   = (const float*)d_in[10];
    const float* W_net   = (const float*)d_in[11];
    const float* b_net   = (const float*)d_in[12];
    const float* g_mul   = (const float*)d_in[13];
    const float* be_mul  = (const float*)d_in[14];
    const float* g_phy   = (const float*)d_in[15];
    const float* be_phy  = (const float*)d_in[16];
    const float* g_net   = (const float*)d_in[17];
    const float* be_net  = (const float*)d_in[18];
    const float* W_out   = (const float*)d_in[19];
    const float* b_out   = (const float*)d_in[20];
    const float* W_pout  = (const float*)d_in[21];
    const float* b_pout  = (const float*)d_in[22];
    const float* W_nout  = (const float*)d_in[23];
    const float* b_nout  = (const float*)d_in[24];

    float* outf = (float*)d_out;
    float* out_phy  = outf;            // 32000
    float* out_net  = outf + 32000;    // 96000
    float* out_idx  = outf + 128000;   // 20000 (idx_mul as floats)
    float* out_xnet = outf + 148000;   // 2048000
    float* out_xphy = outf + 2196000;  // 2048000

    char* ws = (char*)d_ws;
    size_t off = 0;
    auto alloc = [&](size_t bytes) -> void* {
        void* p = (void*)(ws + off);
        off += bytes;
        off = (off + 255) & ~(size_t)255;
        return p;
    };
    int* idxM = (int*)alloc(20000 * 4);
    int* idxP = (int*)alloc(20000 * 4);
    int* idxN = (int*)alloc(20000 * 4);
    double* inv_nrm = (double*)alloc(3000 * 8);
    double* psum = (double*)alloc(256 * 64 * 8);
    double* psq  = (double*)alloc(256 * 64 * 8);
    float* ssM = (float*)alloc(128 * 4);
    float* ssP = (float*)alloc(128 * 4);
    float* ssN = (float*)alloc(128 * 4);
    float* A  = (float*)alloc((size_t)NROWS * D * 4);  // h_share -> h_phy
    float* Bb = (float*)alloc((size_t)NROWS * D * 4);  // t_mul   -> h_net
    float* C  = (float*)alloc((size_t)NROWS * D * 4);  // out_mid -> t_phy
    float* Dd = (float*)alloc((size_t)NROWS * D * 4);  // t_net

    // 1. graphs (f64 cosine, exact ranking), all three in one dispatch
    norms_kernel<<<dim3(4, 3), 256, 0, stream>>>(mul_emb, phy_emb, net_emb, inv_nrm);
    topk_all_kernel<<<dim3(1000, 3), 256, 0, stream>>>(mul_emb, phy_emb, net_emb, inv_nrm,
                                                       idxM, idxP, idxN, out_idx);

    // 2. mul path
    rowgemm_kernel<60><<<8000, 256, 0, stream>>>(data, 60, 0, W_share, b_share, A);
    gcn_kernel<<<8000, 256, 0, stream>>>(A, idxM, mul_emb, Bb, (float*)nullptr);
    bn_partial_kernel<<<256, 256, 0, stream>>>(Bb, psum, psq);
    bn_final_kernel<<<1, 64, 0, stream>>>(psum, psq, g_mul, be_mul, ssM);
    bn_gemm64_kernel<<<8000, 256, 0, stream>>>(Bb, ssM, W_out, b_out, C);

    // 3. phy / net heads
    rowgemm_kernel<16><<<8000, 256, 0, stream>>>(C, 64, 0, W_phy, b_phy, A);
    rowgemm_kernel<48><<<8000, 256, 0, stream>>>(C, 64, 16, W_net, b_net, Bb);
    gcn_kernel<<<8000, 256, 0, stream>>>(A, idxP, phy_emb, C, out_xphy);
    gcn_kernel<<<8000, 256, 0, stream>>>(Bb, idxN, net_emb, Dd, out_xnet);

    bn_partial_kernel<<<256, 256, 0, stream>>>(C, psum, psq);
    bn_final_kernel<<<1, 64, 0, stream>>>(psum, psq, g_phy, be_phy, ssP);
    phy_out_kernel<<<8000, 256, 0, stream>>>(C, ssP, W_pout, b_pout, out_phy);

    bn_partial_kernel<<<256, 256, 0, stream>>>(Dd, psum, psq);
    bn_final_kernel<<<1, 64, 0, stream>>>(psum, psq, g_net, be_net, ssN);
    net_out_kernel<<<8000, 256, 0, stream>>>(Dd, ssN, W_nout, b_nout, out_net);
}

// Round 5
// 316.584 us; speedup vs baseline: 2.3060x; 1.0057x over previous
//
#include <hip/hip_runtime.h>

#define NNODE 1000
#define D 64
#define K_TOP 20
#define NROWS 32000   // B*N = 32*1000

// ---------------- inverse norms (f64) ----------------
__global__ void norms_kernel(const float* __restrict__ e0, const float* __restrict__ e1,
                             const float* __restrict__ e2, double* __restrict__ inv_nrm) {
    int g = blockIdx.y;
    const float* e = (g == 0) ? e0 : ((g == 1) ? e1 : e2);
    int j = blockIdx.x * 256 + threadIdx.x;
    if (j < NNODE) {
        double s = 0.0;
        #pragma unroll
        for (int k = 0; k < D; ++k) { double v = (double)e[j * D + k]; s += v * v; }
        inv_nrm[g * NNODE + j] = 1.0 / sqrt(s);
    }
}

// ---------------- top-20 cosine: one block per 2 query rows ----------------
// Each wave owns 256 candidates (4/lane), extracts its local top-20 for BOTH
// queries with zero barriers (two interleaved shfl-argmax chains -> 2x ILP).
// Then one barrier + parallel rank-merge of the 4 wave lists per query.
// f64 dots in the same FMA order as prior passing rounds -> identical values.
// Tie rule everywhere: equal value -> smaller index (jax top_k).
__global__ void topk_all_kernel(const float* __restrict__ e0, const float* __restrict__ e1,
                                const float* __restrict__ e2, const double* __restrict__ inv_nrm,
                                int* __restrict__ idxM, int* __restrict__ idxP,
                                int* __restrict__ idxN, float* __restrict__ idxf_out) {
    int g = blockIdx.y;
    const float* emb = (g == 0) ? e0 : ((g == 1) ? e1 : e2);
    int* idx_out = (g == 0) ? idxM : ((g == 1) ? idxP : idxN);
    const double* inv = inv_nrm + g * NNODE;

    int i0 = blockIdx.x * 2;       // queries i0, i0+1 (grid.x = 500)
    int tid = threadIdx.x;
    int w = tid >> 6, l = tid & 63;

    __shared__ float srow[2][D];
    __shared__ double sval[2][4][K_TOP];
    __shared__ int   sidx[2][4][K_TOP];
    if (tid < 2 * D) srow[tid >> 6][tid & 63] = emb[(i0 + (tid >> 6)) * D + (tid & 63)];
    __syncthreads();

    double inv_i0 = inv[i0];
    double inv_i1 = inv[i0 + 1];
    const float4* sr0 = (const float4*)srow[0];
    const float4* sr1 = (const float4*)srow[1];

    // 4 candidates per thread, dotted against both query rows
    double val0[4], val1[4];
    #pragma unroll
    for (int t = 0; t < 4; ++t) {
        int j = t * 256 + tid;
        int jc = (j < NNODE) ? j : 0;
        const float4* ej = (const float4*)(emb + (size_t)jc * D);
        double a0 = 0.0, a1 = 0.0;
        #pragma unroll
        for (int q = 0; q < 16; ++q) {
            float4 v = ej[q];
            float4 r0 = sr0[q];
            float4 r1 = sr1[q];
            a0 = fma((double)v.x, (double)r0.x, a0);
            a0 = fma((double)v.y, (double)r0.y, a0);
            a0 = fma((double)v.z, (double)r0.z, a0);
            a0 = fma((double)v.w, (double)r0.w, a0);
            a1 = fma((double)v.x, (double)r1.x, a1);
            a1 = fma((double)v.y, (double)r1.y, a1);
            a1 = fma((double)v.z, (double)r1.z, a1);
            a1 = fma((double)v.w, (double)r1.w, a1);
        }
        double invj = inv[jc];
        val0[t] = (j < NNODE) ? a0 * inv_i0 * invj : -1.0e301;
        val1[t] = (j < NNODE) ? a1 * inv_i1 * invj : -1.0e301;
    }

    // running local maxima (ascending t, strict > : smaller j wins in-thread)
    double lmax0 = -1.0e302, lmax1 = -1.0e302;
    int lidx0 = 0x7fffffff, lidx1 = 0x7fffffff;
    #pragma unroll
    for (int t = 0; t < 4; ++t) {
        if (val0[t] > lmax0) { lmax0 = val0[t]; lidx0 = t * 256 + tid; }
        if (val1[t] > lmax1) { lmax1 = val1[t]; lidx1 = t * 256 + tid; }
    }

    // wave-local top-20 for both queries, no barriers
    for (int rr = 0; rr < K_TOP; ++rr) {
        double bv0 = lmax0, bv1 = lmax1;
        int bi0 = lidx0, bi1 = lidx1;
        #pragma unroll
        for (int s = 1; s < 64; s <<= 1) {
            double ov0 = __shfl_xor(bv0, s, 64);
            int    oi0 = __shfl_xor(bi0, s, 64);
            double ov1 = __shfl_xor(bv1, s, 64);
            int    oi1 = __shfl_xor(bi1, s, 64);
            if (ov0 > bv0 || (ov0 == bv0 && oi0 < bi0)) { bv0 = ov0; bi0 = oi0; }
            if (ov1 > bv1 || (ov1 == bv1 && oi1 < bi1)) { bv1 = ov1; bi1 = oi1; }
        }
        if (l == 0) {
            sval[0][w][rr] = bv0; sidx[0][w][rr] = bi0;
            sval[1][w][rr] = bv1; sidx[1][w][rr] = bi1;
        }
        if (bi0 == lidx0) {
            #pragma unroll
            for (int t = 0; t < 4; ++t)
                if (t * 256 + tid == bi0) val0[t] = -1.0e301;
            lmax0 = -1.0e302; lidx0 = 0x7fffffff;
            #pragma unroll
            for (int t = 0; t < 4; ++t)
                if (val0[t] > lmax0) { lmax0 = val0[t]; lidx0 = t * 256 + tid; }
        }
        if (bi1 == lidx1) {
            #pragma unroll
            for (int t = 0; t < 4; ++t)
                if (t * 256 + tid == bi1) val1[t] = -1.0e301;
            lmax1 = -1.0e302; lidx1 = 0x7fffffff;
            #pragma unroll
            for (int t = 0; t < 4; ++t)
                if (val1[t] > lmax1) { lmax1 = val1[t]; lidx1 = t * 256 + tid; }
        }
    }
    __syncthreads();

    // parallel rank-merge: wave 0 -> q0, wave 1 -> q1.
    // Element e of list lw at pos r: global rank = r + sum over other lists of
    // count-greater (strict (val,idx) order). rank<20 -> write at slot rank.
    if (w < 2) {
        int q = w;
        int i = i0 + q;
        for (int e = l; e < 4 * K_TOP; e += 64) {
            int lw = e / K_TOP, r = e % K_TOP;
            double v = sval[q][lw][r];
            int id = sidx[q][lw][r];
            int rank = r;
            #pragma unroll
            for (int ow = 0; ow < 4; ++ow) {
                if (ow == lw) continue;
                #pragma unroll
                for (int m = 0; m < K_TOP; ++m) {
                    double a = sval[q][ow][m];
                    int ai = sidx[q][ow][m];
                    rank += (a > v || (a == v && ai < id)) ? 1 : 0;
                }
            }
            if (rank < K_TOP) {
                idx_out[i * K_TOP + rank] = id;
                if (g == 0) idxf_out[i * K_TOP + rank] = (float)id;
            }
        }
    }
}

// ---------------- row GEMM: out[row][c] = bias[c] + sum_k X[row][k]*W[k][c] ----------------
template <int K>
__global__ void rowgemm_kernel(const float* __restrict__ X, int ldx,
                               const float* __restrict__ W, const float* __restrict__ bias,
                               float* __restrict__ out) {
    __shared__ float Ws[K * D];
    __shared__ float xs[4][K];
    int tid = threadIdx.x;
    for (int e = tid; e < K * D; e += 256) Ws[e] = W[e];
    int base_row = blockIdx.x * 4;
    for (int e = tid; e < 4 * K; e += 256) {
        int r = e / K, k = e % K;
        xs[r][k] = X[(size_t)(base_row + r) * ldx + k];
    }
    __syncthreads();
    int lr = tid >> 6, c = tid & 63;
    float acc = bias[c];
    #pragma unroll
    for (int k = 0; k < K; ++k) acc = fmaf(xs[lr][k], Ws[k * D + c], acc);
    out[(size_t)(base_row + lr) * D + c] = acc;
}

// ---------------- dual head GEMM: reads C once, emits h_phy (K=16) + h_net (K=48) ----------------
__global__ void rowgemm_dual_kernel(const float* __restrict__ C,
                                    const float* __restrict__ Wp, const float* __restrict__ bp,
                                    const float* __restrict__ Wn, const float* __restrict__ bn_,
                                    float* __restrict__ outP, float* __restrict__ outN) {
    __shared__ float Wps[16 * D];
    __shared__ float Wns[48 * D];
    __shared__ float xs[4][D];
    int tid = threadIdx.x;
    for (int e = tid; e < 16 * D; e += 256) Wps[e] = Wp[e];
    for (int e = tid; e < 48 * D; e += 256) Wns[e] = Wn[e];
    int base_row = blockIdx.x * 4;
    for (int e = tid; e < 4 * D; e += 256)
        xs[e >> 6][e & 63] = C[(size_t)base_row * D + e];
    __syncthreads();
    int lr = tid >> 6, c = tid & 63;
    float ap = bp[c];
    #pragma unroll
    for (int k = 0; k < 16; ++k) ap = fmaf(xs[lr][k], Wps[k * D + c], ap);
    float an = bn_[c];
    #pragma unroll
    for (int k = 0; k < 48; ++k) an = fmaf(xs[lr][16 + k], Wns[k * D + c], an);
    outP[(size_t)(base_row + lr) * D + c] = ap;
    outN[(size_t)(base_row + lr) * D + c] = an;
}

// ---------------- GCN gather-mean-relu (+optional x output), t = y*emb ----------------
__device__ __forceinline__ void gcn_body(const float* __restrict__ h, const int* __restrict__ idx,
                                         const float* __restrict__ emb, float* __restrict__ t_out,
                                         float* __restrict__ x_out, int blk) {
    __shared__ int nbrs[4][K_TOP];
    int tid = threadIdx.x;
    int lr = tid >> 6, c = tid & 63;
    int row = blk * 4 + lr;
    int b = row / NNODE, i = row % NNODE;
    if (c < K_TOP) nbrs[lr][c] = idx[i * K_TOP + c];
    __syncthreads();
    const float* hb = h + (size_t)b * NNODE * D;
    float s = 0.f;
    #pragma unroll
    for (int t = 0; t < K_TOP; ++t) s += hb[(size_t)nbrs[lr][t] * D + c];
    float y = fmaxf(s * (1.0f / 20.0f), 0.f);
    if (x_out) x_out[(size_t)row * D + c] = y;
    t_out[(size_t)row * D + c] = y * emb[i * D + c];
}

__global__ void gcn_kernel(const float* __restrict__ h, const int* __restrict__ idx,
                           const float* __restrict__ emb, float* __restrict__ t_out,
                           float* __restrict__ x_out) {
    gcn_body(h, idx, emb, t_out, x_out, blockIdx.x);
}

__global__ void gcn_dual_kernel(const float* __restrict__ hA, const int* __restrict__ idxA,
                                const float* __restrict__ embA, float* __restrict__ tA,
                                float* __restrict__ xA,
                                const float* __restrict__ hB, const int* __restrict__ idxB,
                                const float* __restrict__ embB, float* __restrict__ tB,
                                float* __restrict__ xB) {
    if (blockIdx.y == 0) gcn_body(hA, idxA, embA, tA, xA, blockIdx.x);
    else                 gcn_body(hB, idxB, embB, tB, xB, blockIdx.x);
}

// ---------------- BN stats: per-block partial sums (f64, deterministic) ----------------
__device__ __forceinline__ void bn_partial_body(const float* __restrict__ t,
                                                double* __restrict__ psum,
                                                double* __restrict__ psq, int blk) {
    __shared__ double sh[256], sh2[256];
    int tid = threadIdx.x;
    const float* base = t + (size_t)blk * 125 * D;
    double s = 0.0, ss = 0.0;
    for (int e = tid; e < 125 * D; e += 256) {
        double v = (double)base[e];
        s += v; ss += v * v;
    }
    sh[tid] = s; sh2[tid] = ss;
    __syncthreads();
    if (tid < 128) { sh[tid] += sh[tid + 128]; sh2[tid] += sh2[tid + 128]; }
    __syncthreads();
    if (tid < 64) {
        psum[(size_t)blk * D + tid] = sh[tid] + sh[tid + 64];
        psq[(size_t)blk * D + tid] = sh2[tid] + sh2[tid + 64];
    }
}

__global__ void bn_partial_kernel(const float* __restrict__ t, double* __restrict__ psum,
                                  double* __restrict__ psq) {
    bn_partial_body(t, psum, psq, blockIdx.x);
}

__global__ void bn_partial_dual_kernel(const float* __restrict__ tA, const float* __restrict__ tB,
                                       double* __restrict__ psum, double* __restrict__ psq) {
    // bank 0: tA, bank 1: tB
    if (blockIdx.y == 0) bn_partial_body(tA, psum, psq, blockIdx.x);
    else                 bn_partial_body(tB, psum + 256 * D, psq + 256 * D, blockIdx.x);
}

__device__ __forceinline__ void bn_final_body(const double* __restrict__ psum,
                                              const double* __restrict__ psq,
                                              const float* __restrict__ g,
                                              const float* __restrict__ beta,
                                              float* __restrict__ ss_out) {
    int c = threadIdx.x;
    if (c < D) {
        double s = 0.0, sq = 0.0;
        for (int b2 = 0; b2 < 256; ++b2) { s += psum[b2 * D + c]; sq += psq[b2 * D + c]; }
        const double n = (double)NROWS;
        double mu = s / n;
        double var = sq / n - mu * mu;
        double inv = 1.0 / sqrt(var + 1e-5);
        double sc = (double)g[c] * inv;
        ss_out[c] = (float)sc;
        ss_out[D + c] = (float)((double)beta[c] - mu * sc);
    }
}

__global__ void bn_final_kernel(const double* __restrict__ psum, const double* __restrict__ psq,
                                const float* __restrict__ g, const float* __restrict__ beta,
                                float* __restrict__ ss_out) {
    bn_final_body(psum, psq, g, beta, ss_out);
}

__global__ void bn_final_dual_kernel(const double* __restrict__ psum, const double* __restrict__ psq,
                                     const float* __restrict__ gP, const float* __restrict__ beP,
                                     const float* __restrict__ gN, const float* __restrict__ beN,
                                     float* __restrict__ ssP, float* __restrict__ ssN) {
    if (blockIdx.x == 0) bn_final_body(psum, psq, gP, beP, ssP);
    else                 bn_final_body(psum + 256 * D, psq + 256 * D, gN, beN, ssN);
}

// ---------------- BN-apply + 64x64 GEMM ----------------
__global__ void bn_gemm64_kernel(const float* __restrict__ t, const float* __restrict__ ss,
                                 const float* __restrict__ W, const float* __restrict__ bias,
                                 float* __restrict__ out) {
    __shared__ float Ws[D * D];
    __shared__ float v[4][D];
    int tid = threadIdx.x;
    for (int e = tid; e < D * D; e += 256) Ws[e] = W[e];
    int lr = tid >> 6, c = tid & 63;
    int row = blockIdx.x * 4 + lr;
    float x = t[(size_t)row * D + c];
    v[lr][c] = fmaxf(fmaf(x, ss[c], ss[D + c]), 0.f);
    __syncthreads();
    float acc = bias[c];
    #pragma unroll
    for (int k = 0; k < D; ++k) acc = fmaf(v[lr][k], Ws[k * D + c], acc);
    out[(size_t)row * D + c] = acc;
}

// ---------------- fused heads: BN-apply + 64->1 (phy) / 64->3 (net) ----------------
__global__ void heads_kernel(const float* __restrict__ tP, const float* __restrict__ ssP,
                             const float* __restrict__ Wp, const float* __restrict__ bp,
                             float* __restrict__ outP,
                             const float* __restrict__ tN, const float* __restrict__ ssN,
                             const float* __restrict__ Wn, const float* __restrict__ bn_,
                             float* __restrict__ outN) {
    int tid = threadIdx.x;
    int lr = tid >> 6, c = tid & 63;
    int row = blockIdx.x * 4 + lr;
    if (blockIdx.y == 0) {
        float x = tP[(size_t)row * D + c];
        float bnv = fmaxf(fmaf(x, ssP[c], ssP[D + c]), 0.f);
        float p = bnv * Wp[c];
        #pragma unroll
        for (int s = 32; s > 0; s >>= 1) p += __shfl_down(p, s, 64);
        if (c == 0) outP[row] = p + bp[0];
    } else {
        float x = tN[(size_t)row * D + c];
        float bnv = fmaxf(fmaf(x, ssN[c], ssN[D + c]), 0.f);
        float p0 = bnv * Wn[c * 3 + 0];
        float p1 = bnv * Wn[c * 3 + 1];
        float p2 = bnv * Wn[c * 3 + 2];
        #pragma unroll
        for (int s = 32; s > 0; s >>= 1) {
            p0 += __shfl_down(p0, s, 64);
            p1 += __shfl_down(p1, s, 64);
            p2 += __shfl_down(p2, s, 64);
        }
        if (c == 0) {
            outN[(size_t)row * 3 + 0] = p0 + bn_[0];
            outN[(size_t)row * 3 + 1] = p1 + bn_[1];
            outN[(size_t)row * 3 + 2] = p2 + bn_[2];
        }
    }
}

extern "C" void kernel_launch(void* const* d_in, const int* in_sizes, int n_in,
                              void* d_out, int out_size, void* d_ws, size_t ws_size,
                              hipStream_t stream) {
    const float* data    = (const float*)d_in[0];
    // d_in[1..3] = edge_index arrays: unused by the reference
    const float* mul_emb = (const float*)d_in[4];
    const float* phy_emb = (const float*)d_in[5];
    const float* net_emb = (const float*)d_in[6];
    const float* W_share = (const float*)d_in[7];
    const float* b_share = (const float*)d_in[8];
    const float* W_phy   = (const float*)d_in[9];
    const float* b_phy   = (const float*)d_in[10];
    const float* W_net   = (const float*)d_in[11];
    const float* b_net   = (const float*)d_in[12];
    const float* g_mul   = (const float*)d_in[13];
    const float* be_mul  = (const float*)d_in[14];
    const float* g_phy   = (const float*)d_in[15];
    const float* be_phy  = (const float*)d_in[16];
    const float* g_net   = (const float*)d_in[17];
    const float* be_net  = (const float*)d_in[18];
    const float* W_out   = (const float*)d_in[19];
    const float* b_out   = (const float*)d_in[20];
    const float* W_pout  = (const float*)d_in[21];
    const float* b_pout  = (const float*)d_in[22];
    const float* W_nout  = (const float*)d_in[23];
    const float* b_nout  = (const float*)d_in[24];

    float* outf = (float*)d_out;
    float* out_phy  = outf;            // 32000
    float* out_net  = outf + 32000;    // 96000
    float* out_idx  = outf + 128000;   // 20000 (idx_mul as floats)
    float* out_xnet = outf + 148000;   // 2048000
    float* out_xphy = outf + 2196000;  // 2048000

    char* ws = (char*)d_ws;
    size_t off = 0;
    auto alloc = [&](size_t bytes) -> void* {
        void* p = (void*)(ws + off);
        off += bytes;
        off = (off + 255) & ~(size_t)255;
        return p;
    };
    int* idxM = (int*)alloc(20000 * 4);
    int* idxP = (int*)alloc(20000 * 4);
    int* idxN = (int*)alloc(20000 * 4);
    double* inv_nrm = (double*)alloc(3000 * 8);
    double* psum = (double*)alloc(2 * 256 * 64 * 8);   // 2 banks
    double* psq  = (double*)alloc(2 * 256 * 64 * 8);
    float* ssM = (float*)alloc(128 * 4);
    float* ssP = (float*)alloc(128 * 4);
    float* ssN = (float*)alloc(128 * 4);
    float* A  = (float*)alloc((size_t)NROWS * D * 4);  // h_share -> h_phy
    float* Bb = (float*)alloc((size_t)NROWS * D * 4);  // t_mul   -> h_net
    float* C  = (float*)alloc((size_t)NROWS * D * 4);  // out_mid -> t_phy
    float* Dd = (float*)alloc((size_t)NROWS * D * 4);  // t_net

    // 1. graphs (f64 cosine, exact ranking)
    norms_kernel<<<dim3(4, 3), 256, 0, stream>>>(mul_emb, phy_emb, net_emb, inv_nrm);
    topk_all_kernel<<<dim3(500, 3), 256, 0, stream>>>(mul_emb, phy_emb, net_emb, inv_nrm,
                                                      idxM, idxP, idxN, out_idx);

    // 2. mul path
    rowgemm_kernel<60><<<8000, 256, 0, stream>>>(data, 60, W_share, b_share, A);
    gcn_kernel<<<8000, 256, 0, stream>>>(A, idxM, mul_emb, Bb, (float*)nullptr);
    bn_partial_kernel<<<256, 256, 0, stream>>>(Bb, psum, psq);
    bn_final_kernel<<<1, 64, 0, stream>>>(psum, psq, g_mul, be_mul, ssM);
    bn_gemm64_kernel<<<8000, 256, 0, stream>>>(Bb, ssM, W_out, b_out, C);

    // 3. phy / net heads (fused pairs)
    rowgemm_dual_kernel<<<8000, 256, 0, stream>>>(C, W_phy, b_phy, W_net, b_net, A, Bb);
    gcn_dual_kernel<<<dim3(8000, 2), 256, 0, stream>>>(A, idxP, phy_emb, C, out_xphy,
                                                       Bb, idxN, net_emb, Dd, out_xnet);
    bn_partial_dual_kernel<<<dim3(256, 2), 256, 0, stream>>>(C, Dd, psum, psq);
    bn_final_dual_kernel<<<2, 64, 0, stream>>>(psum, psq, g_phy, be_phy, g_net, be_net, ssP, ssN);
    heads_kernel<<<dim3(8000, 2), 256, 0, stream>>>(C, ssP, W_pout, b_pout, out_phy,
                                                    Dd, ssN, W_nout, b_nout, out_net);
}